// Round 2
// baseline (188.152 us; speedup 1.0000x reference)
//
#include <hip/hip_runtime.h>
#include <stdint.h>

// Problem constants
#define T_SEQ   2048
#define DMODEL  2048
#define NH      16
#define HD      128
#define QKVN    3072
#define KCOL    2048   // col offset of k in qkv
#define VCOL    2560   // col offset of v in qkv

typedef __bf16 bf16x8 __attribute__((ext_vector_type(8)));
typedef float  f32x4  __attribute__((ext_vector_type(4)));
typedef unsigned short u16x8 __attribute__((ext_vector_type(8)));

__device__ __forceinline__ uint16_t f2bf(float f) {
    uint32_t u = __builtin_bit_cast(uint32_t, f);
    u += 0x7fffu + ((u >> 16) & 1u);
    return (uint16_t)(u >> 16);
}
__device__ __forceinline__ u16x8 ld8(const uint16_t* p) {
    return *reinterpret_cast<const u16x8*>(p);
}
__device__ __forceinline__ void st8(uint16_t* p, u16x8 v) {
    *reinterpret_cast<u16x8*>(p) = v;
}
__device__ __forceinline__ bf16x8 as_bf(u16x8 v) { return __builtin_bit_cast(bf16x8, v); }

// async global->LDS, 16B per lane; LDS dest = wave-uniform base + lane*16
__device__ __forceinline__ void gl_lds16(const uint16_t* g, uint16_t* l) {
    __builtin_amdgcn_global_load_lds((const __attribute__((address_space(1))) void*)g,
                                     (__attribute__((address_space(3))) void*)l, 16, 0, 0);
}

// ---------------------------------------------------------------- cast x -> bf16
__global__ __launch_bounds__(256) void k_cast(const float* __restrict__ in,
                                              uint16_t* __restrict__ out, int n8) {
    int i = blockIdx.x * 256 + threadIdx.x;
    if (i >= n8) return;
    const f32x4* p = reinterpret_cast<const f32x4*>(in) + (size_t)i * 2;
    f32x4 a = p[0], b = p[1];
    u16x8 o;
    o[0] = f2bf(a[0]); o[1] = f2bf(a[1]); o[2] = f2bf(a[2]); o[3] = f2bf(a[3]);
    o[4] = f2bf(b[0]); o[5] = f2bf(b[1]); o[6] = f2bf(b[2]); o[7] = f2bf(b[3]);
    reinterpret_cast<u16x8*>(out)[i] = o;
}

// ---------------------------------------------- transpose-cast f32 [R][C] -> bf16 [C][R]
__global__ __launch_bounds__(256) void k_tcast(const float* __restrict__ in,
                                               uint16_t* __restrict__ out, int R, int C) {
    __shared__ uint16_t tile[64][72];
    int t = threadIdx.x;
    int rbase = blockIdx.y * 64, cbase = blockIdx.x * 64;
#pragma unroll
    for (int p = 0; p < 4; ++p) {
        int ir = p * 16 + (t >> 4);
        int ic = (t & 15) * 4;
        f32x4 v = *reinterpret_cast<const f32x4*>(&in[(size_t)(rbase + ir) * C + cbase + ic]);
        tile[ir][ic + 0] = f2bf(v[0]);
        tile[ir][ic + 1] = f2bf(v[1]);
        tile[ir][ic + 2] = f2bf(v[2]);
        tile[ir][ic + 3] = f2bf(v[3]);
    }
    __syncthreads();
#pragma unroll
    for (int p = 0; p < 2; ++p) {
        int oc = p * 32 + (t >> 3);
        int orr = (t & 7) * 8;
        u16x8 o;
#pragma unroll
        for (int e = 0; e < 8; ++e) o[e] = tile[orr + e][oc];
        st8(&out[(size_t)(cbase + oc) * R + rbase + orr], o);
    }
}

// -------------------------------- transpose bf16: in [R][ldin] cols [coff,coff+C) -> out [C][R]
__global__ __launch_bounds__(256) void k_tbf16(const uint16_t* __restrict__ in,
                                               uint16_t* __restrict__ out,
                                               int R, int C, int ldin, int coff) {
    __shared__ uint16_t tile[64][72];
    int t = threadIdx.x;
    int rbase = blockIdx.y * 64, cbase = blockIdx.x * 64;
#pragma unroll
    for (int p = 0; p < 2; ++p) {
        int ir = p * 32 + (t >> 3);
        int ic = (t & 7) * 8;
        u16x8 v = ld8(&in[(size_t)(rbase + ir) * ldin + coff + cbase + ic]);
#pragma unroll
        for (int e = 0; e < 8; ++e) tile[ir][ic + e] = v[e];
    }
    __syncthreads();
#pragma unroll
    for (int p = 0; p < 2; ++p) {
        int oc = p * 32 + (t >> 3);
        int orr = (t & 7) * 8;
        u16x8 o;
#pragma unroll
        for (int e = 0; e < 8; ++e) o[e] = tile[orr + e][oc];
        st8(&out[(size_t)(cbase + oc) * R + rbase + orr], o);
    }
}

// ---------------------------------------------------------------- GEMM C = A @ Bt^T
// A: [M][K] bf16 row-major; Bt: [N][K] bf16 row-major; C: [M][N] bf16 or f32.
// 128x128 tile, BK=32, 4 waves. global_load_lds staging with source-pre-swizzle,
// double-buffered LDS, one barrier per K-step.
__global__ __launch_bounds__(256) void k_gemm(const uint16_t* __restrict__ A,
                                              const uint16_t* __restrict__ Bt,
                                              void* __restrict__ Cout,
                                              int M, int N, int K,
                                              int out_bf16, int scale_cols, float qscale) {
    __shared__ __align__(16) uint16_t Asm[2][128 * 32];
    __shared__ __align__(16) uint16_t Bsm[2][128 * 32];
    int t = threadIdx.x;
    int w = t >> 6, lane = t & 63, lo = lane & 15, g4 = lane >> 4;
    int mbase = blockIdx.y * 128, nbase = blockIdx.x * 128;
    int moff = (w >> 1) * 64, noff = (w & 1) * 64;

    // staging geometry: wave w stages chunks {2w, 2w+1}; chunk = 16 rows x 32 cols (1 KB)
    // lane l -> row = chunk*16 + l/4, colgroup = l&3 (8 u16 = 16B each)
    // source column pre-swizzled so LDS linear + swizzled ds_read works:
    // u16 idx swizzle = idx ^ (((row>>1)&3)<<3)  ->  cg_src = cg ^ ((row>>1)&3)
    int srow0 = w * 32 + (lane >> 2);
    int srow1 = srow0 + 16;
    int cg0 = ((lane & 3) ^ ((srow0 >> 1) & 3)) * 8;
    int cg1 = ((lane & 3) ^ ((srow1 >> 1) & 3)) * 8;
    const uint16_t* pA0 = A + (size_t)(mbase + srow0) * K + cg0;
    const uint16_t* pA1 = A + (size_t)(mbase + srow1) * K + cg1;
    const uint16_t* pB0 = Bt + (size_t)(nbase + srow0) * K + cg0;
    const uint16_t* pB1 = Bt + (size_t)(nbase + srow1) * K + cg1;
    int lofs0 = (w * 2) * 512, lofs1 = lofs0 + 512;

    f32x4 acc[4][4] = {};

    // prologue: stage tile 0 into buf 0
    gl_lds16(pA0, &Asm[0][lofs0]); gl_lds16(pA1, &Asm[0][lofs1]);
    gl_lds16(pB0, &Bsm[0][lofs0]); gl_lds16(pB1, &Bsm[0][lofs1]);

    int cur = 0;
    for (int kt = 0; kt < K; kt += 32) {
        __syncthreads();  // drains vmcnt -> buf[cur] ready; prev reads of buf[cur^1] done
        if (kt + 32 < K) {
            int ko = kt + 32;
            gl_lds16(pA0 + ko, &Asm[cur ^ 1][lofs0]); gl_lds16(pA1 + ko, &Asm[cur ^ 1][lofs1]);
            gl_lds16(pB0 + ko, &Bsm[cur ^ 1][lofs0]); gl_lds16(pB1 + ko, &Bsm[cur ^ 1][lofs1]);
        }
        bf16x8 af[4], bfr[4];
#pragma unroll
        for (int i = 0; i < 4; ++i) {
            int ar = moff + i * 16 + lo;
            af[i] = as_bf(ld8(&Asm[cur][(ar * 32 + g4 * 8) ^ (((ar >> 1) & 3) << 3)]));
            int br = noff + i * 16 + lo;
            bfr[i] = as_bf(ld8(&Bsm[cur][(br * 32 + g4 * 8) ^ (((br >> 1) & 3) << 3)]));
        }
#pragma unroll
        for (int i = 0; i < 4; ++i)
#pragma unroll
            for (int j = 0; j < 4; ++j)
                acc[i][j] = __builtin_amdgcn_mfma_f32_16x16x32_bf16(af[i], bfr[j], acc[i][j], 0, 0, 0);
        cur ^= 1;
    }

    if (out_bf16) {
        uint16_t* C = (uint16_t*)Cout;
#pragma unroll
        for (int i = 0; i < 4; ++i)
#pragma unroll
            for (int j = 0; j < 4; ++j)
#pragma unroll
                for (int r = 0; r < 4; ++r) {
                    int row = mbase + moff + i * 16 + g4 * 4 + r;
                    int col = nbase + noff + j * 16 + lo;
                    float v = acc[i][j][r];
                    if (col < scale_cols) v *= qscale;
                    C[(size_t)row * N + col] = f2bf(v);
                }
    } else {
        float* C = (float*)Cout;
#pragma unroll
        for (int i = 0; i < 4; ++i)
#pragma unroll
            for (int j = 0; j < 4; ++j)
#pragma unroll
                for (int r = 0; r < 4; ++r) {
                    int row = mbase + moff + i * 16 + g4 * 4 + r;
                    int col = nbase + noff + j * 16 + lo;
                    C[(size_t)row * N + col] = acc[i][j][r];
                }
    }
}

// ---------------------------------------------------------------- causal GQA flash attention
// qkv: [T][3072] bf16 (q pre-scaled); vt: [512][T] bf16 (row = kh*128+d); ao: [T][2048] bf16
// Grid (16,16): block x processes q-tiles {x, 31-x} serially -> every block = 33 KV-iters.
// K/V double-buffered in LDS via global_load_lds (source-pre-swizzled), 1 barrier/iter.
__global__ __launch_bounds__(256) void k_attn(const uint16_t* __restrict__ qkv,
                                              const uint16_t* __restrict__ vt,
                                              uint16_t* __restrict__ ao) {
    __shared__ __align__(16) uint16_t Ksm[2][64 * 128];   // [j][d] linear, data pre-swizzled
    __shared__ __align__(16) uint16_t Vsm[2][128 * 64];   // [d][j] linear, data pre-swizzled
    __shared__ __align__(16) uint16_t Psm[4][16 * 64];    // per-wave [i][j], swizzled
    int t = threadIdx.x;
    int w = t >> 6, lane = t & 63, lo = lane & 15, g4 = lane >> 4;
    int x = blockIdx.x, h = blockIdx.y, kh = h >> 2;

    const uint16_t* kbase = qkv + KCOL + (size_t)kh * HD;
    const uint16_t* vbase = vt + (size_t)(kh * HD) * T_SEQ;

    // staging pointers for jb=0; swizzle: u16 idx ^ ((row&7)<<3) -> src colgroup = cg ^ (row&7)
    // K: chunk ch = w*4+c covers rows [4ch,4ch+4) of [64][128]; lane -> row 4ch + l/16, cg = l&15
    // V: chunk ch covers d-rows [8ch,8ch+8) of [128][64]; lane -> d 8ch + l/8, cg = l&7
    const uint16_t* kp[4]; const uint16_t* vp[4]; int lofs[4];
#pragma unroll
    for (int c = 0; c < 4; ++c) {
        int ch = w * 4 + c;
        int kr = ch * 4 + (lane >> 4);
        kp[c] = kbase + (size_t)kr * QKVN + ((lane & 15) ^ (kr & 7)) * 8;
        int vr = ch * 8 + (lane >> 3);
        vp[c] = vbase + (size_t)vr * T_SEQ + ((lane & 7) ^ (vr & 7)) * 8;
        lofs[c] = ch * 512;
    }

    for (int rep = 0; rep < 2; ++rep) {
        int qt = rep ? 31 - x : x;
        int qb = qt * 64;
        int n = qt + 1;

        bf16x8 qf[4];
        {
            int qrow = qb + w * 16 + lo;
            const uint16_t* qp = &qkv[(size_t)qrow * QKVN + h * HD + g4 * 8];
#pragma unroll
            for (int ks = 0; ks < 4; ++ks) qf[ks] = as_bf(ld8(qp + ks * 32));
        }

        f32x4 o[8] = {};
        float mr[4], lr[4];
#pragma unroll
        for (int r = 0; r < 4; ++r) { mr[r] = -INFINITY; lr[r] = 0.f; }

        __syncthreads();  // all waves done reading previous rep's buffers
#pragma unroll
        for (int c = 0; c < 4; ++c) {
            gl_lds16(kp[c], &Ksm[0][lofs[c]]);
            gl_lds16(vp[c], &Vsm[0][lofs[c]]);
        }

        int cur = 0;
        for (int jt = 0; jt < n; ++jt) {
            __syncthreads();  // buf[cur] staged (vmcnt drained); buf[cur^1] free
            if (jt + 1 < n) {
                size_t ko = (size_t)(jt + 1) * 64 * QKVN;
                int vo = (jt + 1) * 64;
#pragma unroll
                for (int c = 0; c < 4; ++c) {
                    gl_lds16(kp[c] + ko, &Ksm[cur ^ 1][lofs[c]]);
                    gl_lds16(vp[c] + vo, &Vsm[cur ^ 1][lofs[c]]);
                }
            }

            // QK^T: s[nt] covers kv cols nt*16+lo
            f32x4 s[4] = {};
#pragma unroll
            for (int nt = 0; nt < 4; ++nt) {
                int j = nt * 16 + lo;
#pragma unroll
                for (int ks = 0; ks < 4; ++ks) {
                    bf16x8 b = as_bf(ld8(&Ksm[cur][(j * 128 + ks * 32 + g4 * 8) ^ ((lo & 7) << 3)]));
                    s[nt] = __builtin_amdgcn_mfma_f32_16x16x32_bf16(qf[ks], b, s[nt], 0, 0, 0);
                }
            }

            if (jt == qt) {  // diagonal tile: mask j > i (local coords)
#pragma unroll
                for (int nt = 0; nt < 4; ++nt)
#pragma unroll
                    for (int r = 0; r < 4; ++r) {
                        int j = nt * 16 + lo;
                        int i = w * 16 + g4 * 4 + r;
                        if (j > i) s[nt][r] = -INFINITY;
                    }
            }

            // online softmax
            float pm[4];
#pragma unroll
            for (int r = 0; r < 4; ++r) {
                pm[r] = fmaxf(fmaxf(s[0][r], s[1][r]), fmaxf(s[2][r], s[3][r]));
                pm[r] = fmaxf(pm[r], __shfl_xor(pm[r], 1));
                pm[r] = fmaxf(pm[r], __shfl_xor(pm[r], 2));
                pm[r] = fmaxf(pm[r], __shfl_xor(pm[r], 4));
                pm[r] = fmaxf(pm[r], __shfl_xor(pm[r], 8));
            }
            float al[4];
#pragma unroll
            for (int r = 0; r < 4; ++r) {
                float mn = fmaxf(mr[r], pm[r]);
                al[r] = __expf(mr[r] - mn);
                mr[r] = mn;
            }
            float ps[4] = {0.f, 0.f, 0.f, 0.f};
#pragma unroll
            for (int nt = 0; nt < 4; ++nt)
#pragma unroll
                for (int r = 0; r < 4; ++r) {
                    float p = __expf(s[nt][r] - mr[r]);
                    s[nt][r] = p;
                    ps[r] += p;
                }
#pragma unroll
            for (int nt = 0; nt < 4; ++nt)
#pragma unroll
                for (int r = 0; r < 4; ++r) {
                    int i = g4 * 4 + r, j = nt * 16 + lo;
                    Psm[w][(i * 64 + j) ^ ((i & 7) << 3)] = f2bf(s[nt][r]);
                }
#pragma unroll
            for (int r = 0; r < 4; ++r) {
                ps[r] += __shfl_xor(ps[r], 1);
                ps[r] += __shfl_xor(ps[r], 2);
                ps[r] += __shfl_xor(ps[r], 4);
                ps[r] += __shfl_xor(ps[r], 8);
                lr[r] = lr[r] * al[r] + ps[r];
            }
#pragma unroll
            for (int dt = 0; dt < 8; ++dt)
#pragma unroll
                for (int r = 0; r < 4; ++r) o[dt][r] *= al[r];

            // PV
#pragma unroll
            for (int ks2 = 0; ks2 < 2; ++ks2) {
                bf16x8 pa = as_bf(ld8(&Psm[w][(lo * 64 + ks2 * 32 + g4 * 8) ^ ((lo & 7) << 3)]));
#pragma unroll
                for (int dt = 0; dt < 8; ++dt) {
                    int d = dt * 16 + lo;
                    bf16x8 vb = as_bf(ld8(&Vsm[cur][(d * 64 + ks2 * 32 + g4 * 8) ^ ((lo & 7) << 3)]));
                    o[dt] = __builtin_amdgcn_mfma_f32_16x16x32_bf16(pa, vb, o[dt], 0, 0, 0);
                }
            }
            cur ^= 1;
        }

        // epilogue: ao[i][h*128 + d] = o / l
#pragma unroll
        for (int dt = 0; dt < 8; ++dt)
#pragma unroll
            for (int r = 0; r < 4; ++r) {
                int i = qb + w * 16 + g4 * 4 + r;
                int col = h * HD + dt * 16 + lo;
                ao[(size_t)i * DMODEL + col] = f2bf(o[dt][r] / lr[r]);
            }
    }
}

// ---------------------------------------------------------------- launch
extern "C" void kernel_launch(void* const* d_in, const int* in_sizes, int n_in,
                              void* d_out, int out_size, void* d_ws, size_t ws_size,
                              hipStream_t stream) {
    (void)in_sizes; (void)n_in; (void)out_size; (void)ws_size;
    const float* x    = (const float*)d_in[0];
    const float* Wqkv = (const float*)d_in[1];
    const float* Wo   = (const float*)d_in[2];
    float* out = (float*)d_out;

    char* ws = (char*)d_ws;
    uint16_t* xb   = (uint16_t*)(ws + 0);          //  8 MB  x bf16 [2048][2048]
    uint16_t* wqt  = (uint16_t*)(ws + 8388608);    // 12 MB  Wqkv^T bf16 [3072][2048]
    uint16_t* wot  = (uint16_t*)(ws + 20971520);   //  8 MB  Wo^T bf16 [2048][2048]
    uint16_t* qkvb = (uint16_t*)(ws + 29360128);   // 12 MB  qkv bf16 [2048][3072]
    uint16_t* vtb  = (uint16_t*)(ws + 41943040);   //  2 MB  v^T bf16 [512][2048]
    uint16_t* aob  = (uint16_t*)(ws + 44040192);   //  8 MB  attn out bf16 [2048][2048]

    const float qscale = 0.08838834764831845f;  // 1/sqrt(128)

    k_cast<<<2048, 256, 0, stream>>>(x, xb, 524288);
    k_tcast<<<dim3(48, 32), 256, 0, stream>>>(Wqkv, wqt, 2048, 3072);
    k_tcast<<<dim3(32, 32), 256, 0, stream>>>(Wo, wot, 2048, 2048);
    k_gemm<<<dim3(24, 16), 256, 0, stream>>>(xb, wqt, qkvb, 2048, 3072, 2048, 1, 2048, qscale);
    k_tbf16<<<dim3(8, 32), 256, 0, stream>>>(qkvb, vtb, 2048, 512, 3072, 2560);
    k_attn<<<dim3(16, 16), 256, 0, stream>>>(qkvb, vtb, aob);
    k_gemm<<<dim3(16, 16), 256, 0, stream>>>(aob, wot, out, 2048, 2048, 2048, 0, 0, 1.0f);
}

// Round 3
// 159.642 us; speedup vs baseline: 1.1786x; 1.1786x over previous
//
#include <hip/hip_runtime.h>
#include <stdint.h>

// Problem constants
#define T_SEQ   2048
#define DMODEL  2048
#define NH      16
#define HD      128
#define QKVN    3072
#define KCOL    2048   // col offset of k in qkv
#define VCOL    2560   // col offset of v in qkv

typedef __bf16 bf16x8 __attribute__((ext_vector_type(8)));
typedef float  f32x4  __attribute__((ext_vector_type(4)));
typedef unsigned short u16x8 __attribute__((ext_vector_type(8)));

__device__ __forceinline__ uint16_t f2bf(float f) {
    uint32_t u = __builtin_bit_cast(uint32_t, f);
    u += 0x7fffu + ((u >> 16) & 1u);
    return (uint16_t)(u >> 16);
}
__device__ __forceinline__ float bf2f(uint16_t u) {
    return __builtin_bit_cast(float, (uint32_t)u << 16);
}
__device__ __forceinline__ u16x8 ld8(const uint16_t* p) {
    return *reinterpret_cast<const u16x8*>(p);
}
__device__ __forceinline__ void st8(uint16_t* p, u16x8 v) {
    *reinterpret_cast<u16x8*>(p) = v;
}
__device__ __forceinline__ bf16x8 as_bf(u16x8 v) { return __builtin_bit_cast(bf16x8, v); }

// async global->LDS, 16B per lane; LDS dest = wave-uniform base + lane*16
__device__ __forceinline__ void gl_lds16(const uint16_t* g, uint16_t* l) {
    __builtin_amdgcn_global_load_lds((const __attribute__((address_space(1))) void*)g,
                                     (__attribute__((address_space(3))) void*)l, 16, 0, 0);
}

// ---------------------------------------------------------------- cast x -> bf16
__global__ __launch_bounds__(256) void k_cast(const float* __restrict__ in,
                                              uint16_t* __restrict__ out, int n8) {
    int i = blockIdx.x * 256 + threadIdx.x;
    if (i >= n8) return;
    const f32x4* p = reinterpret_cast<const f32x4*>(in) + (size_t)i * 2;
    f32x4 a = p[0], b = p[1];
    u16x8 o;
    o[0] = f2bf(a[0]); o[1] = f2bf(a[1]); o[2] = f2bf(a[2]); o[3] = f2bf(a[3]);
    o[4] = f2bf(b[0]); o[5] = f2bf(b[1]); o[6] = f2bf(b[2]); o[7] = f2bf(b[3]);
    reinterpret_cast<u16x8*>(out)[i] = o;
}

// ---------------------------------------------- transpose-cast f32 [R][C] -> bf16 [C][R]
__global__ __launch_bounds__(256) void k_tcast(const float* __restrict__ in,
                                               uint16_t* __restrict__ out, int R, int C) {
    __shared__ uint16_t tile[64][72];
    int t = threadIdx.x;
    int rbase = blockIdx.y * 64, cbase = blockIdx.x * 64;
#pragma unroll
    for (int p = 0; p < 4; ++p) {
        int ir = p * 16 + (t >> 4);
        int ic = (t & 15) * 4;
        f32x4 v = *reinterpret_cast<const f32x4*>(&in[(size_t)(rbase + ir) * C + cbase + ic]);
        tile[ir][ic + 0] = f2bf(v[0]);
        tile[ir][ic + 1] = f2bf(v[1]);
        tile[ir][ic + 2] = f2bf(v[2]);
        tile[ir][ic + 3] = f2bf(v[3]);
    }
    __syncthreads();
#pragma unroll
    for (int p = 0; p < 2; ++p) {
        int oc = p * 32 + (t >> 3);
        int orr = (t & 7) * 8;
        u16x8 o;
#pragma unroll
        for (int e = 0; e < 8; ++e) o[e] = tile[orr + e][oc];
        st8(&out[(size_t)(cbase + oc) * R + rbase + orr], o);
    }
}

// -------------------------------- transpose bf16: in [R][ldin] cols [coff,coff+C) -> out [C][R]
__global__ __launch_bounds__(256) void k_tbf16(const uint16_t* __restrict__ in,
                                               uint16_t* __restrict__ out,
                                               int R, int C, int ldin, int coff) {
    __shared__ uint16_t tile[64][72];
    int t = threadIdx.x;
    int rbase = blockIdx.y * 64, cbase = blockIdx.x * 64;
#pragma unroll
    for (int p = 0; p < 2; ++p) {
        int ir = p * 32 + (t >> 3);
        int ic = (t & 7) * 8;
        u16x8 v = ld8(&in[(size_t)(rbase + ir) * ldin + coff + cbase + ic]);
#pragma unroll
        for (int e = 0; e < 8; ++e) tile[ir][ic + e] = v[e];
    }
    __syncthreads();
#pragma unroll
    for (int p = 0; p < 2; ++p) {
        int oc = p * 32 + (t >> 3);
        int orr = (t & 7) * 8;
        u16x8 o;
#pragma unroll
        for (int e = 0; e < 8; ++e) o[e] = tile[orr + e][oc];
        st8(&out[(size_t)(cbase + oc) * R + rbase + orr], o);
    }
}

// ---------------------------------------------------------------- GEMM C = A @ Bt^T
// A: [M][K] bf16 row-major; Bt: [N][K] bf16 row-major; C: [M][N] bf16 or f32.
// 128x128 tile, BK=32, 4 waves. global_load_lds staging with source-pre-swizzle,
// double-buffered LDS, one barrier per K-step.
__global__ __launch_bounds__(256) void k_gemm(const uint16_t* __restrict__ A,
                                              const uint16_t* __restrict__ Bt,
                                              void* __restrict__ Cout,
                                              int M, int N, int K,
                                              int out_bf16, int scale_cols, float qscale) {
    __shared__ __align__(16) uint16_t Asm[2][128 * 32];
    __shared__ __align__(16) uint16_t Bsm[2][128 * 32];
    int t = threadIdx.x;
    int w = t >> 6, lane = t & 63, lo = lane & 15, g4 = lane >> 4;
    int mbase = blockIdx.y * 128, nbase = blockIdx.x * 128;
    int moff = (w >> 1) * 64, noff = (w & 1) * 64;

    int srow0 = w * 32 + (lane >> 2);
    int srow1 = srow0 + 16;
    int cg0 = ((lane & 3) ^ ((srow0 >> 1) & 3)) * 8;
    int cg1 = ((lane & 3) ^ ((srow1 >> 1) & 3)) * 8;
    const uint16_t* pA0 = A + (size_t)(mbase + srow0) * K + cg0;
    const uint16_t* pA1 = A + (size_t)(mbase + srow1) * K + cg1;
    const uint16_t* pB0 = Bt + (size_t)(nbase + srow0) * K + cg0;
    const uint16_t* pB1 = Bt + (size_t)(nbase + srow1) * K + cg1;
    int lofs0 = (w * 2) * 512, lofs1 = lofs0 + 512;

    f32x4 acc[4][4] = {};

    gl_lds16(pA0, &Asm[0][lofs0]); gl_lds16(pA1, &Asm[0][lofs1]);
    gl_lds16(pB0, &Bsm[0][lofs0]); gl_lds16(pB1, &Bsm[0][lofs1]);

    int cur = 0;
    for (int kt = 0; kt < K; kt += 32) {
        __syncthreads();
        if (kt + 32 < K) {
            int ko = kt + 32;
            gl_lds16(pA0 + ko, &Asm[cur ^ 1][lofs0]); gl_lds16(pA1 + ko, &Asm[cur ^ 1][lofs1]);
            gl_lds16(pB0 + ko, &Bsm[cur ^ 1][lofs0]); gl_lds16(pB1 + ko, &Bsm[cur ^ 1][lofs1]);
        }
        bf16x8 af[4], bfr[4];
#pragma unroll
        for (int i = 0; i < 4; ++i) {
            int ar = moff + i * 16 + lo;
            af[i] = as_bf(ld8(&Asm[cur][(ar * 32 + g4 * 8) ^ (((ar >> 1) & 3) << 3)]));
            int br = noff + i * 16 + lo;
            bfr[i] = as_bf(ld8(&Bsm[cur][(br * 32 + g4 * 8) ^ (((br >> 1) & 3) << 3)]));
        }
        __builtin_amdgcn_s_setprio(1);
#pragma unroll
        for (int i = 0; i < 4; ++i)
#pragma unroll
            for (int j = 0; j < 4; ++j)
                acc[i][j] = __builtin_amdgcn_mfma_f32_16x16x32_bf16(af[i], bfr[j], acc[i][j], 0, 0, 0);
        __builtin_amdgcn_s_setprio(0);
        cur ^= 1;
    }

    if (out_bf16) {
        uint16_t* C = (uint16_t*)Cout;
#pragma unroll
        for (int i = 0; i < 4; ++i)
#pragma unroll
            for (int j = 0; j < 4; ++j)
#pragma unroll
                for (int r = 0; r < 4; ++r) {
                    int row = mbase + moff + i * 16 + g4 * 4 + r;
                    int col = nbase + noff + j * 16 + lo;
                    float v = acc[i][j][r];
                    if (col < scale_cols) v *= qscale;
                    C[(size_t)row * N + col] = f2bf(v);
                }
    } else {
        float* C = (float*)Cout;
#pragma unroll
        for (int i = 0; i < 4; ++i)
#pragma unroll
            for (int j = 0; j < 4; ++j)
#pragma unroll
                for (int r = 0; r < 4; ++r) {
                    int row = mbase + moff + i * 16 + g4 * 4 + r;
                    int col = nbase + noff + j * 16 + lo;
                    C[(size_t)row * N + col] = acc[i][j][r];
                }
    }
}

// ---------------------------------------------------------------- causal GQA flash attention
// Split-KV x2: grid (16,16,2). Block (x,h,p): q-tiles {x, 31-x} serially; KV tiles jt = p mod 2.
// Emits partial numerator o (bf16) + (m,l) f32 per row; k_comb merges the two parts.
// po: [2][T][NH*HD] bf16; pml: [2][T][NH][2] f32
__global__ __launch_bounds__(256) void k_attn(const uint16_t* __restrict__ qkv,
                                              const uint16_t* __restrict__ vt,
                                              uint16_t* __restrict__ po,
                                              float* __restrict__ pml) {
    __shared__ __align__(16) uint16_t Ksm[2][64 * 128];   // [j][d] linear, data pre-swizzled
    __shared__ __align__(16) uint16_t Vsm[2][128 * 64];   // [d][j] linear, data pre-swizzled
    __shared__ __align__(16) uint16_t Psm[4][16 * 64];    // per-wave [i][j], swizzled
    int t = threadIdx.x;
    int w = t >> 6, lane = t & 63, lo = lane & 15, g4 = lane >> 4;
    int x = blockIdx.x, h = blockIdx.y, p = blockIdx.z, kh = h >> 2;

    const uint16_t* kbase = qkv + KCOL + (size_t)kh * HD;
    const uint16_t* vbase = vt + (size_t)(kh * HD) * T_SEQ;

    // staging pointers (jb-relative); swizzle: u16 idx ^ ((row&7)<<3) -> src colgroup ^= (row&7)
    const uint16_t* kp[4]; const uint16_t* vp[4]; int lofs[4];
#pragma unroll
    for (int c = 0; c < 4; ++c) {
        int ch = w * 4 + c;
        int kr = ch * 4 + (lane >> 4);
        kp[c] = kbase + (size_t)kr * QKVN + ((lane & 15) ^ (kr & 7)) * 8;
        int vr = ch * 8 + (lane >> 3);
        vp[c] = vbase + (size_t)vr * T_SEQ + ((lane & 7) ^ (vr & 7)) * 8;
        lofs[c] = ch * 512;
    }

    for (int rep = 0; rep < 2; ++rep) {
        int qt = rep ? 31 - x : x;
        int qb = qt * 64;
        int cnt = (qt + 2 - p) >> 1;  // jt in {p, p+2, ...} <= qt

        bf16x8 qf[4];
        {
            int qrow = qb + w * 16 + lo;
            const uint16_t* qp = &qkv[(size_t)qrow * QKVN + h * HD + g4 * 8];
#pragma unroll
            for (int ks = 0; ks < 4; ++ks) qf[ks] = as_bf(ld8(qp + ks * 32));
        }

        f32x4 o[8] = {};
        float mr[4], pp[4];
#pragma unroll
        for (int r = 0; r < 4; ++r) { mr[r] = -INFINITY; pp[r] = 0.f; }

        if (cnt) {
            __syncthreads();  // protect buffers still being read (prev rep)
            size_t ko = (size_t)p * 64 * QKVN; int vo = p * 64;
#pragma unroll
            for (int c = 0; c < 4; ++c) {
                gl_lds16(kp[c] + ko, &Ksm[0][lofs[c]]);
                gl_lds16(vp[c] + vo, &Vsm[0][lofs[c]]);
            }
        }

        int cur = 0;
        for (int it = 0; it < cnt; ++it) {
            int jt = p + 2 * it;
            __syncthreads();  // buf[cur] staged (vmcnt drained); buf[cur^1] free
            if (it + 1 < cnt) {
                size_t ko = (size_t)(jt + 2) * 64 * QKVN;
                int vo = (jt + 2) * 64;
#pragma unroll
                for (int c = 0; c < 4; ++c) {
                    gl_lds16(kp[c] + ko, &Ksm[cur ^ 1][lofs[c]]);
                    gl_lds16(vp[c] + vo, &Vsm[cur ^ 1][lofs[c]]);
                }
            }

            // QK^T
            f32x4 s[4] = {};
            __builtin_amdgcn_s_setprio(1);
#pragma unroll
            for (int nt = 0; nt < 4; ++nt) {
                int j = nt * 16 + lo;
#pragma unroll
                for (int ks = 0; ks < 4; ++ks) {
                    bf16x8 b = as_bf(ld8(&Ksm[cur][(j * 128 + ks * 32 + g4 * 8) ^ ((lo & 7) << 3)]));
                    s[nt] = __builtin_amdgcn_mfma_f32_16x16x32_bf16(qf[ks], b, s[nt], 0, 0, 0);
                }
            }
            __builtin_amdgcn_s_setprio(0);

            if (jt == qt) {  // diagonal tile: mask j > i (local coords)
#pragma unroll
                for (int nt = 0; nt < 4; ++nt)
#pragma unroll
                    for (int r = 0; r < 4; ++r) {
                        int j = nt * 16 + lo;
                        int i = w * 16 + g4 * 4 + r;
                        if (j > i) s[nt][r] = -INFINITY;
                    }
            }

            // tile max (cross-lane reduce over lo group)
            float pm[4];
#pragma unroll
            for (int r = 0; r < 4; ++r) {
                pm[r] = fmaxf(fmaxf(s[0][r], s[1][r]), fmaxf(s[2][r], s[3][r]));
                pm[r] = fmaxf(pm[r], __shfl_xor(pm[r], 1));
                pm[r] = fmaxf(pm[r], __shfl_xor(pm[r], 2));
                pm[r] = fmaxf(pm[r], __shfl_xor(pm[r], 4));
                pm[r] = fmaxf(pm[r], __shfl_xor(pm[r], 8));
            }
            // defer-max: only rescale when max grew by > 8
            bool grow = false;
#pragma unroll
            for (int r = 0; r < 4; ++r) grow = grow || (pm[r] > mr[r] + 8.f);
            if (__any(grow)) {
#pragma unroll
                for (int r = 0; r < 4; ++r) {
                    float mn = fmaxf(mr[r], pm[r]);
                    float al = __expf(mr[r] - mn);
                    mr[r] = mn;
                    pp[r] *= al;
#pragma unroll
                    for (int dt = 0; dt < 8; ++dt) o[dt][r] *= al;
                }
            }
            // P = exp(s - mr); per-lane partial sum (l-reduce deferred to end)
#pragma unroll
            for (int nt = 0; nt < 4; ++nt)
#pragma unroll
                for (int r = 0; r < 4; ++r) {
                    float pe = __expf(s[nt][r] - mr[r]);
                    s[nt][r] = pe;
                    pp[r] += pe;
                }
#pragma unroll
            for (int nt = 0; nt < 4; ++nt)
#pragma unroll
                for (int r = 0; r < 4; ++r) {
                    int i = g4 * 4 + r, j = nt * 16 + lo;
                    Psm[w][(i * 64 + j) ^ ((i & 7) << 3)] = f2bf(s[nt][r]);
                }

            // PV
            __builtin_amdgcn_s_setprio(1);
#pragma unroll
            for (int ks2 = 0; ks2 < 2; ++ks2) {
                bf16x8 pa = as_bf(ld8(&Psm[w][(lo * 64 + ks2 * 32 + g4 * 8) ^ ((lo & 7) << 3)]));
#pragma unroll
                for (int dt = 0; dt < 8; ++dt) {
                    int d = dt * 16 + lo;
                    bf16x8 vb = as_bf(ld8(&Vsm[cur][(d * 64 + ks2 * 32 + g4 * 8) ^ ((lo & 7) << 3)]));
                    o[dt] = __builtin_amdgcn_mfma_f32_16x16x32_bf16(pa, vb, o[dt], 0, 0, 0);
                }
            }
            __builtin_amdgcn_s_setprio(0);
            cur ^= 1;
        }

        // final l reduce (deferred)
        float lr[4];
#pragma unroll
        for (int r = 0; r < 4; ++r) {
            float ps = pp[r];
            ps += __shfl_xor(ps, 1);
            ps += __shfl_xor(ps, 2);
            ps += __shfl_xor(ps, 4);
            ps += __shfl_xor(ps, 8);
            lr[r] = ps;
        }

        // partial epilogue
        uint16_t* pob = po + (size_t)p * T_SEQ * DMODEL;
#pragma unroll
        for (int dt = 0; dt < 8; ++dt)
#pragma unroll
            for (int r = 0; r < 4; ++r) {
                int i = qb + w * 16 + g4 * 4 + r;
                int col = h * HD + dt * 16 + lo;
                pob[(size_t)i * DMODEL + col] = f2bf(o[dt][r]);
            }
        if (lo == 0) {
#pragma unroll
            for (int r = 0; r < 4; ++r) {
                int i = qb + w * 16 + g4 * 4 + r;
                float* pe = pml + ((size_t)(p * T_SEQ + i) * NH + h) * 2;
                pe[0] = mr[r];
                pe[1] = lr[r];
            }
        }
    }
}

// ---------------------------------------------------------------- combine split-KV partials
__global__ __launch_bounds__(256) void k_comb(const uint16_t* __restrict__ po,
                                              const float* __restrict__ pml,
                                              uint16_t* __restrict__ ao) {
    int i = blockIdx.x * 256 + threadIdx.x;   // 524288 threads
    int row = i >> 8;
    int cg = i & 255;
    int h = cg >> 4;
    int col = cg * 8;
    const float* p0 = pml + ((size_t)row * NH + h) * 2;
    const float* p1 = pml + ((size_t)(T_SEQ + row) * NH + h) * 2;
    float m0 = p0[0], l0 = p0[1], m1 = p1[0], l1 = p1[1];
    float m = fmaxf(m0, m1);
    float w0 = __expf(m0 - m), w1 = __expf(m1 - m);
    float rl = 1.f / (l0 * w0 + l1 * w1);
    size_t off = (size_t)row * DMODEL + col;
    u16x8 a = ld8(po + off);
    u16x8 b = ld8(po + (size_t)T_SEQ * DMODEL + off);
    u16x8 o;
#pragma unroll
    for (int e = 0; e < 8; ++e)
        o[e] = f2bf((bf2f(a[e]) * w0 + bf2f(b[e]) * w1) * rl);
    st8(ao + off, o);
}

// ---------------------------------------------------------------- launch
extern "C" void kernel_launch(void* const* d_in, const int* in_sizes, int n_in,
                              void* d_out, int out_size, void* d_ws, size_t ws_size,
                              hipStream_t stream) {
    (void)in_sizes; (void)n_in; (void)out_size; (void)ws_size;
    const float* x    = (const float*)d_in[0];
    const float* Wqkv = (const float*)d_in[1];
    const float* Wo   = (const float*)d_in[2];
    float* out = (float*)d_out;

    char* ws = (char*)d_ws;
    uint16_t* xb   = (uint16_t*)(ws + 0);          //  8 MB  x bf16 [2048][2048]   (dead after GEMM1)
    uint16_t* wqt  = (uint16_t*)(ws + 8388608);    // 12 MB  Wqkv^T bf16          (dead after GEMM1)
    uint16_t* wot  = (uint16_t*)(ws + 20971520);   //  8 MB  Wo^T bf16
    uint16_t* qkvb = (uint16_t*)(ws + 29360128);   // 12 MB  qkv bf16 [2048][3072]
    uint16_t* vtb  = (uint16_t*)(ws + 41943040);   //  2 MB  v^T bf16 [512][2048]
    uint16_t* aob  = (uint16_t*)(ws + 44040192);   //  8 MB  attn out bf16 [2048][2048]
    // split-KV partials overlay the dead xb/wqt region:
    uint16_t* po   = (uint16_t*)(ws + 0);          // 16 MB  [2][2048][2048] bf16
    float*    pml  = (float*)(ws + 16777216);      // 0.5 MB [2][2048][16][2] f32

    const float qscale = 0.08838834764831845f;  // 1/sqrt(128)

    k_cast<<<2048, 256, 0, stream>>>(x, xb, 524288);
    k_tcast<<<dim3(48, 32), 256, 0, stream>>>(Wqkv, wqt, 2048, 3072);
    k_tcast<<<dim3(32, 32), 256, 0, stream>>>(Wo, wot, 2048, 2048);
    k_gemm<<<dim3(24, 16), 256, 0, stream>>>(xb, wqt, qkvb, 2048, 3072, 2048, 1, 2048, qscale);
    k_tbf16<<<dim3(8, 32), 256, 0, stream>>>(qkvb, vtb, 2048, 512, 3072, 2560);
    k_attn<<<dim3(16, 16, 2), 256, 0, stream>>>(qkvb, vtb, po, pml);
    k_comb<<<2048, 256, 0, stream>>>(po, pml, aob);
    k_gemm<<<dim3(16, 16), 256, 0, stream>>>(aob, wot, out, 2048, 2048, 2048, 0, 0, 1.0f);
}

// Round 4
// 151.276 us; speedup vs baseline: 1.2438x; 1.0553x over previous
//
#include <hip/hip_runtime.h>
#include <stdint.h>

// Problem constants
#define T_SEQ   2048
#define DMODEL  2048
#define NH      16
#define HD      128
#define QKVN    3072
#define KCOL    2048   // col offset of k in qkv
#define VCOL    2560   // col offset of v in qkv

typedef __bf16 bf16x8 __attribute__((ext_vector_type(8)));
typedef float  f32x4  __attribute__((ext_vector_type(4)));
typedef unsigned short u16x8 __attribute__((ext_vector_type(8)));

__device__ __forceinline__ uint16_t f2bf(float f) {
    uint32_t u = __builtin_bit_cast(uint32_t, f);
    u += 0x7fffu + ((u >> 16) & 1u);
    return (uint16_t)(u >> 16);
}
__device__ __forceinline__ float bf2f(uint16_t u) {
    return __builtin_bit_cast(float, (uint32_t)u << 16);
}
__device__ __forceinline__ u16x8 ld8(const uint16_t* p) {
    return *reinterpret_cast<const u16x8*>(p);
}
__device__ __forceinline__ void st8(uint16_t* p, u16x8 v) {
    *reinterpret_cast<u16x8*>(p) = v;
}
__device__ __forceinline__ bf16x8 as_bf(u16x8 v) { return __builtin_bit_cast(bf16x8, v); }

// async global->LDS, 16B per lane; LDS dest = wave-uniform base + lane*16
__device__ __forceinline__ void gl_lds16(const uint16_t* g, uint16_t* l) {
    __builtin_amdgcn_global_load_lds((const __attribute__((address_space(1))) void*)g,
                                     (__attribute__((address_space(3))) void*)l, 16, 0, 0);
}

// ---------------------------------------------------------------- cast x -> bf16
__global__ __launch_bounds__(256) void k_cast(const float* __restrict__ in,
                                              uint16_t* __restrict__ out, int n8) {
    int i = blockIdx.x * 256 + threadIdx.x;
    if (i >= n8) return;
    const f32x4* p = reinterpret_cast<const f32x4*>(in) + (size_t)i * 2;
    f32x4 a = p[0], b = p[1];
    u16x8 o;
    o[0] = f2bf(a[0]); o[1] = f2bf(a[1]); o[2] = f2bf(a[2]); o[3] = f2bf(a[3]);
    o[4] = f2bf(b[0]); o[5] = f2bf(b[1]); o[6] = f2bf(b[2]); o[7] = f2bf(b[3]);
    reinterpret_cast<u16x8*>(out)[i] = o;
}

// ---------------------------------------------- transpose-cast f32 [R][C] -> bf16 [C][R]
__global__ __launch_bounds__(256) void k_tcast(const float* __restrict__ in,
                                               uint16_t* __restrict__ out, int R, int C) {
    __shared__ uint16_t tile[64][72];
    int t = threadIdx.x;
    int rbase = blockIdx.y * 64, cbase = blockIdx.x * 64;
#pragma unroll
    for (int p = 0; p < 4; ++p) {
        int ir = p * 16 + (t >> 4);
        int ic = (t & 15) * 4;
        f32x4 v = *reinterpret_cast<const f32x4*>(&in[(size_t)(rbase + ir) * C + cbase + ic]);
        tile[ir][ic + 0] = f2bf(v[0]);
        tile[ir][ic + 1] = f2bf(v[1]);
        tile[ir][ic + 2] = f2bf(v[2]);
        tile[ir][ic + 3] = f2bf(v[3]);
    }
    __syncthreads();
#pragma unroll
    for (int p = 0; p < 2; ++p) {
        int oc = p * 32 + (t >> 3);
        int orr = (t & 7) * 8;
        u16x8 o;
#pragma unroll
        for (int e = 0; e < 8; ++e) o[e] = tile[orr + e][oc];
        st8(&out[(size_t)(cbase + oc) * R + rbase + orr], o);
    }
}

// -------------------------------- transpose bf16: in [R][ldin] cols [coff,coff+C) -> out [C][R]
__global__ __launch_bounds__(256) void k_tbf16(const uint16_t* __restrict__ in,
                                               uint16_t* __restrict__ out,
                                               int R, int C, int ldin, int coff) {
    __shared__ uint16_t tile[64][72];
    int t = threadIdx.x;
    int rbase = blockIdx.y * 64, cbase = blockIdx.x * 64;
#pragma unroll
    for (int p = 0; p < 2; ++p) {
        int ir = p * 32 + (t >> 3);
        int ic = (t & 7) * 8;
        u16x8 v = ld8(&in[(size_t)(rbase + ir) * ldin + coff + cbase + ic]);
#pragma unroll
        for (int e = 0; e < 8; ++e) tile[ir][ic + e] = v[e];
    }
    __syncthreads();
#pragma unroll
    for (int p = 0; p < 2; ++p) {
        int oc = p * 32 + (t >> 3);
        int orr = (t & 7) * 8;
        u16x8 o;
#pragma unroll
        for (int e = 0; e < 8; ++e) o[e] = tile[orr + e][oc];
        st8(&out[(size_t)(cbase + oc) * R + rbase + orr], o);
    }
}

// ---------------------------------------------------------------- GEMM C = A @ Bt^T
// A: [M][K] bf16 row-major; Bt: [N][K] bf16 row-major; C: [M][N] bf16 or f32.
// 64(M)x128(N) tile, BK=32, 4 waves (wave-tile 32x64). global_load_lds staging,
// double-buffered LDS, one barrier per K-step. 1D grid, XCD-bijective swizzle,
// column-major tile order within an XCD (B-panel stays L2-resident).
__global__ __launch_bounds__(256) void k_gemm(const uint16_t* __restrict__ A,
                                              const uint16_t* __restrict__ Bt,
                                              void* __restrict__ Cout,
                                              int M, int N, int K, int gy,
                                              int out_bf16, int scale_cols, float qscale) {
    __shared__ __align__(16) uint16_t Asm[2][64 * 32];
    __shared__ __align__(16) uint16_t Bsm[2][128 * 32];
    int t = threadIdx.x;
    int w = t >> 6, lane = t & 63, lo = lane & 15, g4 = lane >> 4;

    // XCD-bijective grid swizzle (nwg % 8 == 0), column-major within XCD
    int nwg = (int)gridDim.x;
    int wg = (int)blockIdx.x;
    int idx = (wg & 7) * (nwg >> 3) + (wg >> 3);
    int bx = idx / gy, by = idx % gy;
    int mbase = by * 64, nbase = bx * 128;

    int wm = w >> 1, wn = w & 1;  // wave-tile: rows wm*32+, cols wn*64+

    // staging: A tile [64][32] = 4 chunks of 1KB (wave w -> chunk w);
    //          B tile [128][32] = 8 chunks (wave w -> chunks 2w, 2w+1)
    int srowA = w * 16 + (lane >> 2);
    int scol = (lane & 3) * 8;
    const uint16_t* pA = A + (size_t)(mbase + srowA) * K + scol;
    int srowB0 = w * 32 + (lane >> 2);
    int srowB1 = srowB0 + 16;
    const uint16_t* pB0 = Bt + (size_t)(nbase + srowB0) * K + scol;
    const uint16_t* pB1 = Bt + (size_t)(nbase + srowB1) * K + scol;
    int lofsA = w * 512, lofsB0 = w * 1024, lofsB1 = lofsB0 + 512;

    f32x4 acc[2][4] = {};

    // prologue: stage tile 0 into buf 0
    gl_lds16(pA, &Asm[0][lofsA]);
    gl_lds16(pB0, &Bsm[0][lofsB0]); gl_lds16(pB1, &Bsm[0][lofsB1]);

    int cur = 0;
    for (int kt = 0; kt < K; kt += 32) {
        __syncthreads();  // drains vmcnt -> buf[cur] ready; prev reads of buf[cur^1] done
        if (kt + 32 < K) {
            int ko = kt + 32;
            gl_lds16(pA + ko, &Asm[cur ^ 1][lofsA]);
            gl_lds16(pB0 + ko, &Bsm[cur ^ 1][lofsB0]); gl_lds16(pB1 + ko, &Bsm[cur ^ 1][lofsB1]);
        }
        bf16x8 af[2], bfr[4];
#pragma unroll
        for (int i = 0; i < 2; ++i) {
            int ar = wm * 32 + i * 16 + lo;
            af[i] = as_bf(ld8(&Asm[cur][ar * 32 + g4 * 8]));
        }
#pragma unroll
        for (int j = 0; j < 4; ++j) {
            int br = wn * 64 + j * 16 + lo;
            bfr[j] = as_bf(ld8(&Bsm[cur][br * 32 + g4 * 8]));
        }
        __builtin_amdgcn_s_setprio(1);
#pragma unroll
        for (int i = 0; i < 2; ++i)
#pragma unroll
            for (int j = 0; j < 4; ++j)
                acc[i][j] = __builtin_amdgcn_mfma_f32_16x16x32_bf16(af[i], bfr[j], acc[i][j], 0, 0, 0);
        __builtin_amdgcn_s_setprio(0);
        cur ^= 1;
    }

    if (out_bf16) {
        uint16_t* C = (uint16_t*)Cout;
#pragma unroll
        for (int i = 0; i < 2; ++i)
#pragma unroll
            for (int j = 0; j < 4; ++j)
#pragma unroll
                for (int r = 0; r < 4; ++r) {
                    int row = mbase + wm * 32 + i * 16 + g4 * 4 + r;
                    int col = nbase + wn * 64 + j * 16 + lo;
                    float v = acc[i][j][r];
                    if (col < scale_cols) v *= qscale;
                    C[(size_t)row * N + col] = f2bf(v);
                }
    } else {
        float* C = (float*)Cout;
#pragma unroll
        for (int i = 0; i < 2; ++i)
#pragma unroll
            for (int j = 0; j < 4; ++j)
#pragma unroll
                for (int r = 0; r < 4; ++r) {
                    int row = mbase + wm * 32 + i * 16 + g4 * 4 + r;
                    int col = nbase + wn * 64 + j * 16 + lo;
                    C[(size_t)row * N + col] = acc[i][j][r];
                }
    }
}

// ---------------------------------------------------------------- causal GQA flash attention
// Split-KV x2: grid (16,16,2). Block (x,h,p): q-tiles {x, 31-x} serially; KV tiles jt = p mod 2.
// Emits partial numerator o (bf16) + (m,l) f32 per row; k_comb merges the two parts.
// po: [2][T][NH*HD] bf16; pml: [2][T][NH][2] f32
__global__ __launch_bounds__(256) void k_attn(const uint16_t* __restrict__ qkv,
                                              const uint16_t* __restrict__ vt,
                                              uint16_t* __restrict__ po,
                                              float* __restrict__ pml) {
    __shared__ __align__(16) uint16_t Ksm[2][64 * 128];   // [j][d] linear, data pre-swizzled
    __shared__ __align__(16) uint16_t Vsm[2][128 * 64];   // [d][j] linear, data pre-swizzled
    __shared__ __align__(16) uint16_t Psm[4][16 * 64];    // per-wave [i][j], swizzled
    int t = threadIdx.x;
    int w = t >> 6, lane = t & 63, lo = lane & 15, g4 = lane >> 4;
    int x = blockIdx.x, h = blockIdx.y, p = blockIdx.z, kh = h >> 2;

    const uint16_t* kbase = qkv + KCOL + (size_t)kh * HD;
    const uint16_t* vbase = vt + (size_t)(kh * HD) * T_SEQ;

    // staging pointers (jb-relative); swizzle: u16 idx ^ ((row&7)<<3) -> src colgroup ^= (row&7)
    const uint16_t* kp[4]; const uint16_t* vp[4]; int lofs[4];
#pragma unroll
    for (int c = 0; c < 4; ++c) {
        int ch = w * 4 + c;
        int kr = ch * 4 + (lane >> 4);
        kp[c] = kbase + (size_t)kr * QKVN + ((lane & 15) ^ (kr & 7)) * 8;
        int vr = ch * 8 + (lane >> 3);
        vp[c] = vbase + (size_t)vr * T_SEQ + ((lane & 7) ^ (vr & 7)) * 8;
        lofs[c] = ch * 512;
    }

    for (int rep = 0; rep < 2; ++rep) {
        int qt = rep ? 31 - x : x;
        int qb = qt * 64;
        int cnt = (qt + 2 - p) >> 1;  // jt in {p, p+2, ...} <= qt

        bf16x8 qf[4];
        {
            int qrow = qb + w * 16 + lo;
            const uint16_t* qp = &qkv[(size_t)qrow * QKVN + h * HD + g4 * 8];
#pragma unroll
            for (int ks = 0; ks < 4; ++ks) qf[ks] = as_bf(ld8(qp + ks * 32));
        }

        f32x4 o[8] = {};
        float mr[4], pp[4];
#pragma unroll
        for (int r = 0; r < 4; ++r) { mr[r] = -INFINITY; pp[r] = 0.f; }

        if (cnt) {
            __syncthreads();  // protect buffers still being read (prev rep)
            size_t ko = (size_t)p * 64 * QKVN; int vo = p * 64;
#pragma unroll
            for (int c = 0; c < 4; ++c) {
                gl_lds16(kp[c] + ko, &Ksm[0][lofs[c]]);
                gl_lds16(vp[c] + vo, &Vsm[0][lofs[c]]);
            }
        }

        int cur = 0;
        for (int it = 0; it < cnt; ++it) {
            int jt = p + 2 * it;
            __syncthreads();  // buf[cur] staged (vmcnt drained); buf[cur^1] free
            if (it + 1 < cnt) {
                size_t ko = (size_t)(jt + 2) * 64 * QKVN;
                int vo = (jt + 2) * 64;
#pragma unroll
                for (int c = 0; c < 4; ++c) {
                    gl_lds16(kp[c] + ko, &Ksm[cur ^ 1][lofs[c]]);
                    gl_lds16(vp[c] + vo, &Vsm[cur ^ 1][lofs[c]]);
                }
            }

            // QK^T
            f32x4 s[4] = {};
            __builtin_amdgcn_s_setprio(1);
#pragma unroll
            for (int nt = 0; nt < 4; ++nt) {
                int j = nt * 16 + lo;
#pragma unroll
                for (int ks = 0; ks < 4; ++ks) {
                    bf16x8 b = as_bf(ld8(&Ksm[cur][(j * 128 + ks * 32 + g4 * 8) ^ ((lo & 7) << 3)]));
                    s[nt] = __builtin_amdgcn_mfma_f32_16x16x32_bf16(qf[ks], b, s[nt], 0, 0, 0);
                }
            }
            __builtin_amdgcn_s_setprio(0);

            if (jt == qt) {  // diagonal tile: mask j > i (local coords)
#pragma unroll
                for (int nt = 0; nt < 4; ++nt)
#pragma unroll
                    for (int r = 0; r < 4; ++r) {
                        int j = nt * 16 + lo;
                        int i = w * 16 + g4 * 4 + r;
                        if (j > i) s[nt][r] = -INFINITY;
                    }
            }

            // tile max (cross-lane reduce over lo group)
            float pm[4];
#pragma unroll
            for (int r = 0; r < 4; ++r) {
                pm[r] = fmaxf(fmaxf(s[0][r], s[1][r]), fmaxf(s[2][r], s[3][r]));
                pm[r] = fmaxf(pm[r], __shfl_xor(pm[r], 1));
                pm[r] = fmaxf(pm[r], __shfl_xor(pm[r], 2));
                pm[r] = fmaxf(pm[r], __shfl_xor(pm[r], 4));
                pm[r] = fmaxf(pm[r], __shfl_xor(pm[r], 8));
            }
            // defer-max: only rescale when max grew by > 8
            bool grow = false;
#pragma unroll
            for (int r = 0; r < 4; ++r) grow = grow || (pm[r] > mr[r] + 8.f);
            if (__any(grow)) {
#pragma unroll
                for (int r = 0; r < 4; ++r) {
                    float mn = fmaxf(mr[r], pm[r]);
                    float al = __expf(mr[r] - mn);
                    mr[r] = mn;
                    pp[r] *= al;
#pragma unroll
                    for (int dt = 0; dt < 8; ++dt) o[dt][r] *= al;
                }
            }
            // P = exp(s - mr); per-lane partial sum (l-reduce deferred to end)
#pragma unroll
            for (int nt = 0; nt < 4; ++nt)
#pragma unroll
                for (int r = 0; r < 4; ++r) {
                    float pe = __expf(s[nt][r] - mr[r]);
                    s[nt][r] = pe;
                    pp[r] += pe;
                }
#pragma unroll
            for (int nt = 0; nt < 4; ++nt)
#pragma unroll
                for (int r = 0; r < 4; ++r) {
                    int i = g4 * 4 + r, j = nt * 16 + lo;
                    Psm[w][(i * 64 + j) ^ ((i & 7) << 3)] = f2bf(s[nt][r]);
                }

            // PV
            __builtin_amdgcn_s_setprio(1);
#pragma unroll
            for (int ks2 = 0; ks2 < 2; ++ks2) {
                bf16x8 pa = as_bf(ld8(&Psm[w][(lo * 64 + ks2 * 32 + g4 * 8) ^ ((lo & 7) << 3)]));
#pragma unroll
                for (int dt = 0; dt < 8; ++dt) {
                    int d = dt * 16 + lo;
                    bf16x8 vb = as_bf(ld8(&Vsm[cur][(d * 64 + ks2 * 32 + g4 * 8) ^ ((lo & 7) << 3)]));
                    o[dt] = __builtin_amdgcn_mfma_f32_16x16x32_bf16(pa, vb, o[dt], 0, 0, 0);
                }
            }
            __builtin_amdgcn_s_setprio(0);
            cur ^= 1;
        }

        // final l reduce (deferred)
        float lr[4];
#pragma unroll
        for (int r = 0; r < 4; ++r) {
            float ps = pp[r];
            ps += __shfl_xor(ps, 1);
            ps += __shfl_xor(ps, 2);
            ps += __shfl_xor(ps, 4);
            ps += __shfl_xor(ps, 8);
            lr[r] = ps;
        }

        // partial epilogue
        uint16_t* pob = po + (size_t)p * T_SEQ * DMODEL;
#pragma unroll
        for (int dt = 0; dt < 8; ++dt)
#pragma unroll
            for (int r = 0; r < 4; ++r) {
                int i = qb + w * 16 + g4 * 4 + r;
                int col = h * HD + dt * 16 + lo;
                pob[(size_t)i * DMODEL + col] = f2bf(o[dt][r]);
            }
        if (lo == 0) {
#pragma unroll
            for (int r = 0; r < 4; ++r) {
                int i = qb + w * 16 + g4 * 4 + r;
                float* pe = pml + ((size_t)(p * T_SEQ + i) * NH + h) * 2;
                pe[0] = mr[r];
                pe[1] = lr[r];
            }
        }
    }
}

// ---------------------------------------------------------------- combine split-KV partials
__global__ __launch_bounds__(256) void k_comb(const uint16_t* __restrict__ po,
                                              const float* __restrict__ pml,
                                              uint16_t* __restrict__ ao) {
    int i = blockIdx.x * 256 + threadIdx.x;   // 524288 threads
    int row = i >> 8;
    int cg = i & 255;
    int h = cg >> 4;
    int col = cg * 8;
    const float* p0 = pml + ((size_t)row * NH + h) * 2;
    const float* p1 = pml + ((size_t)(T_SEQ + row) * NH + h) * 2;
    float m0 = p0[0], l0 = p0[1], m1 = p1[0], l1 = p1[1];
    float m = fmaxf(m0, m1);
    float w0 = __expf(m0 - m), w1 = __expf(m1 - m);
    float rl = 1.f / (l0 * w0 + l1 * w1);
    size_t off = (size_t)row * DMODEL + col;
    u16x8 a = ld8(po + off);
    u16x8 b = ld8(po + (size_t)T_SEQ * DMODEL + off);
    u16x8 o;
#pragma unroll
    for (int e = 0; e < 8; ++e)
        o[e] = f2bf((bf2f(a[e]) * w0 + bf2f(b[e]) * w1) * rl);
    st8(ao + off, o);
}

// ---------------------------------------------------------------- launch
extern "C" void kernel_launch(void* const* d_in, const int* in_sizes, int n_in,
                              void* d_out, int out_size, void* d_ws, size_t ws_size,
                              hipStream_t stream) {
    (void)in_sizes; (void)n_in; (void)out_size; (void)ws_size;
    const float* x    = (const float*)d_in[0];
    const float* Wqkv = (const float*)d_in[1];
    const float* Wo   = (const float*)d_in[2];
    float* out = (float*)d_out;

    char* ws = (char*)d_ws;
    uint16_t* xb   = (uint16_t*)(ws + 0);          //  8 MB  x bf16 [2048][2048]   (dead after GEMM1)
    uint16_t* wqt  = (uint16_t*)(ws + 8388608);    // 12 MB  Wqkv^T bf16          (dead after GEMM1)
    uint16_t* wot  = (uint16_t*)(ws + 20971520);   //  8 MB  Wo^T bf16
    uint16_t* qkvb = (uint16_t*)(ws + 29360128);   // 12 MB  qkv bf16 [2048][3072]
    uint16_t* vtb  = (uint16_t*)(ws + 41943040);   //  2 MB  v^T bf16 [512][2048]
    uint16_t* aob  = (uint16_t*)(ws + 44040192);   //  8 MB  attn out bf16 [2048][2048]
    // split-KV partials overlay the dead xb/wqt region:
    uint16_t* po   = (uint16_t*)(ws + 0);          // 16 MB  [2][2048][2048] bf16
    float*    pml  = (float*)(ws + 16777216);      // 0.5 MB [2][2048][16][2] f32

    const float qscale = 0.08838834764831845f;  // 1/sqrt(128)

    k_cast<<<2048, 256, 0, stream>>>(x, xb, 524288);
    k_tcast<<<dim3(48, 32), 256, 0, stream>>>(Wqkv, wqt, 2048, 3072);
    k_tcast<<<dim3(32, 32), 256, 0, stream>>>(Wo, wot, 2048, 2048);
    // GEMM1: M=2048 (gy=32), N=3072 -> 32*24 = 768 blocks (3/CU balanced)
    k_gemm<<<768, 256, 0, stream>>>(xb, wqt, qkvb, 2048, 3072, 2048, 32, 1, 2048, qscale);
    k_tbf16<<<dim3(8, 32), 256, 0, stream>>>(qkvb, vtb, 2048, 512, 3072, 2560);
    k_attn<<<dim3(16, 16, 2), 256, 0, stream>>>(qkvb, vtb, po, pml);
    k_comb<<<2048, 256, 0, stream>>>(po, pml, aob);
    // GEMM2: M=2048 (gy=32), N=2048 -> 32*16 = 512 blocks (2/CU balanced)
    k_gemm<<<512, 256, 0, stream>>>(aob, wot, out, 2048, 2048, 2048, 32, 0, 0, 1.0f);
}